// Round 1
// baseline (1988.840 us; speedup 1.0000x reference)
//
#include <hip/hip_runtime.h>

#define B   64
#define KK  4096
#define D   256
#define Q   8
#define H   4
#define DH  64
#define HQ  32
#define HM  512
#define EPS 1e-8f
#define LNE 1e-5f
#define SCALE 0.125f

__device__ __forceinline__ float bf2f(unsigned short u) {
    unsigned int x = ((unsigned int)u) << 16;
    float f; __builtin_memcpy(&f, &x, 4); return f;
}
__device__ __forceinline__ unsigned short f2bf(float f) {
    unsigned int x; __builtin_memcpy(&x, &f, 4);
    unsigned int lsb = (x >> 16) & 1u;
    x += 0x7fffu + lsb;
    return (unsigned short)(x >> 16);
}

// K1: LN(inputs) fused with k = xhat@Wk*scale, v = xhat@Wv. 32 rows/block.
__global__ __launch_bounds__(256) void k1_ln_kvproj(
    const float* __restrict__ inp, const float* __restrict__ Wk, const float* __restrict__ Wv,
    const float* __restrict__ lnw, const float* __restrict__ lnb,
    unsigned short* __restrict__ kbuf, unsigned short* __restrict__ vbuf)
{
    __shared__ float xs[32][256];
    const int t = threadIdx.x;
    const size_t row0 = (size_t)blockIdx.x * 32;
    const float4* in4 = (const float4*)(inp + row0 * D);
    float4* xs4 = (float4*)&xs[0][0];
#pragma unroll
    for (int i = 0; i < 8; ++i) xs4[i * 256 + t] = in4[i * 256 + t];
    __syncthreads();
    const int wave = t >> 6, lane = t & 63;
#pragma unroll
    for (int rr = 0; rr < 8; ++rr) {
        const int r = wave * 8 + rr;
        float4 xv = ((float4*)xs[r])[lane];
        float s  = xv.x + xv.y + xv.z + xv.w;
        float ss = xv.x*xv.x + xv.y*xv.y + xv.z*xv.z + xv.w*xv.w;
#pragma unroll
        for (int off = 32; off; off >>= 1) { s += __shfl_xor(s, off); ss += __shfl_xor(ss, off); }
        const float mu = s * (1.f / 256.f);
        const float rs = rsqrtf(ss * (1.f / 256.f) - mu * mu + LNE);
        const float4 w4 = ((const float4*)lnw)[lane];
        const float4 b4 = ((const float4*)lnb)[lane];
        xv.x = (xv.x - mu) * rs * w4.x + b4.x;
        xv.y = (xv.y - mu) * rs * w4.y + b4.y;
        xv.z = (xv.z - mu) * rs * w4.z + b4.z;
        xv.w = (xv.w - mu) * rs * w4.w + b4.w;
        ((float4*)xs[r])[lane] = xv;
    }
    __syncthreads();
    float acck[32], accv[32];
#pragma unroll
    for (int r = 0; r < 32; ++r) { acck[r] = 0.f; accv[r] = 0.f; }
    const int c = t;
    for (int d = 0; d < 256; d += 4) {
        const float* wkp = Wk + (size_t)d * 256 + c;
        const float* wvp = Wv + (size_t)d * 256 + c;
        const float wk0 = wkp[0], wk1 = wkp[256], wk2 = wkp[512], wk3 = wkp[768];
        const float wv0 = wvp[0], wv1 = wvp[256], wv2 = wvp[512], wv3 = wvp[768];
#pragma unroll
        for (int r = 0; r < 32; ++r) {
            const float4 x4 = *(const float4*)&xs[r][d];
            acck[r] = fmaf(x4.w, wk3, fmaf(x4.z, wk2, fmaf(x4.y, wk1, fmaf(x4.x, wk0, acck[r]))));
            accv[r] = fmaf(x4.w, wv3, fmaf(x4.z, wv2, fmaf(x4.y, wv1, fmaf(x4.x, wv0, accv[r]))));
        }
    }
#pragma unroll
    for (int r = 0; r < 32; ++r) {
        const size_t base = (row0 + r) * D + c;
        kbuf[base] = f2bf(acck[r] * SCALE);
        vbuf[base] = f2bf(accv[r]);
    }
}

// K2: LN(slots) + q = s_n @ Wq. One block per (b,q) row.
__global__ __launch_bounds__(256) void k2_qproj(
    const float* __restrict__ slots, const float* __restrict__ Wq,
    const float* __restrict__ lnw, const float* __restrict__ lnb, float* __restrict__ qbuf)
{
    const int row = blockIdx.x, t = threadIdx.x;
    __shared__ float sn[256];
    __shared__ float red[8];
    const float x = slots[(size_t)row * D + t];
    float mu, rs;
    {
        float s = x, ss = x * x;
#pragma unroll
        for (int off = 32; off; off >>= 1) { s += __shfl_xor(s, off); ss += __shfl_xor(ss, off); }
        if ((t & 63) == 0) { red[t >> 6] = s; red[4 + (t >> 6)] = ss; }
        __syncthreads();
        const float S  = red[0] + red[1] + red[2] + red[3];
        const float SS = red[4] + red[5] + red[6] + red[7];
        mu = S * (1.f / 256.f);
        rs = rsqrtf(SS * (1.f / 256.f) - mu * mu + LNE);
    }
    sn[t] = (x - mu) * rs * lnw[t] + lnb[t];
    __syncthreads();
    float acc = 0.f;
    for (int d = 0; d < 256; ++d) acc = fmaf(sn[d], Wq[(size_t)d * 256 + t], acc);
    qbuf[(size_t)row * D + t] = acc;
}

// K3: logits (k . q) + joint softmax over H*Q=32 per (b,kk). One wave per kk row.
__global__ __launch_bounds__(256) void k3_logits(
    const unsigned short* __restrict__ kbuf, const float* __restrict__ qbuf,
    float* __restrict__ pbuf)
{
    const int blk = blockIdx.x;
    const int b = blk >> 10;
    const int kk0 = (blk & 1023) * 4;
    __shared__ float qs[2048];
    __shared__ float ks[4][256];
    const int t = threadIdx.x;
    {
        const float4* q4 = (const float4*)(qbuf + (size_t)b * (Q * D));
        float4* qs4 = (float4*)qs;
        qs4[t] = q4[t];
        qs4[256 + t] = q4[256 + t];
        const ushort4* kp = (const ushort4*)(kbuf + ((size_t)b * KK + kk0) * D);
        const ushort4 u = kp[t];
        const int r = t >> 6, c0 = (t & 63) * 4;
        ks[r][c0 + 0] = bf2f(u.x); ks[r][c0 + 1] = bf2f(u.y);
        ks[r][c0 + 2] = bf2f(u.z); ks[r][c0 + 3] = bf2f(u.w);
    }
    __syncthreads();
    const int wv = t >> 6, lane = t & 63;
    const int hq = lane & 31, h = hq >> 3, q = hq & 7;
    const int half = lane >> 5;
    const float* qrow = qs + q * 256 + h * 64 + half * 32;
    const float* krow = &ks[wv][h * 64 + half * 32];
    float acc = 0.f;
#pragma unroll
    for (int i = 0; i < 32; ++i) {      // (i+lane)&31 rotation: conflict-free LDS
        const int d = (i + lane) & 31;
        acc = fmaf(krow[d], qrow[d], acc);
    }
    acc += __shfl_xor(acc, 32);
    float m = acc;
#pragma unroll
    for (int off = 16; off; off >>= 1) m = fmaxf(m, __shfl_xor(m, off));
    const float e = __expf(acc - m);
    float se = e;
#pragma unroll
    for (int off = 16; off; off >>= 1) se += __shfl_xor(se, off);
    const float p = e / se;
    if (lane < 32)
        pbuf[((size_t)b * KK + kk0 + wv) * HQ + hq] = p;
}

// K4: denominator per (b,h,q): 1 / (sum_k p + K*EPS)
__global__ __launch_bounds__(1024) void k4_sums(
    const float* __restrict__ pbuf, float* __restrict__ invden)
{
    const int b = blockIdx.x, t = threadIdx.x;
    const int hq = t & 31, g = t >> 5;
    const float* pb = pbuf + (size_t)b * KK * HQ;
    float acc = 0.f;
    for (int kk = g; kk < KK; kk += 32)
        acc += pb[(size_t)kk * HQ + hq];
    __shared__ float red[1024];
    red[t] = acc;
    __syncthreads();
    for (int s = 512; s >= 32; s >>= 1) {
        if (t < s) red[t] += red[t + s];
        __syncthreads();
    }
    if (t < 32) invden[b * HQ + t] = 1.f / (red[t] + (float)KK * EPS);
}

// K5: updates[b,q,h*64+d] = sum_k attn_final * v. One block per (b,h).
__global__ __launch_bounds__(256) void k5_updates(
    const float* __restrict__ pbuf, const unsigned short* __restrict__ vbuf,
    const float* __restrict__ invden, float* __restrict__ upd)
{
    const int blk = blockIdx.x;
    const int b = blk >> 2, h = blk & 3;
    const int t = threadIdx.x;
    __shared__ float vs[64][64];
    __shared__ float ps[64][8];
    const int d = t & 63, qg = t >> 6;
    const int sr = t >> 2;
    const int vc0 = (t & 3) * 16;
    const int pq0 = (t & 3) * 2;
    const float invA = invden[b * HQ + h * Q + pq0];
    const float invB = invden[b * HQ + h * Q + pq0 + 1];
    float acc0 = 0.f, acc1 = 0.f;
    for (int kk0 = 0; kk0 < KK; kk0 += 64) {
        __syncthreads();
        {
            const unsigned short* vp = vbuf + (((size_t)b * KK + kk0 + sr) * D + h * DH + vc0);
            const uint4 A  = *(const uint4*)vp;
            const uint4 Bq = *(const uint4*)(vp + 8);
            const unsigned int aw[4] = {A.x, A.y, A.z, A.w};
            const unsigned int bw[4] = {Bq.x, Bq.y, Bq.z, Bq.w};
#pragma unroll
            for (int i = 0; i < 4; ++i) {
                vs[sr][vc0 + 2 * i]         = bf2f((unsigned short)(aw[i] & 0xffffu));
                vs[sr][vc0 + 2 * i + 1]     = bf2f((unsigned short)(aw[i] >> 16));
                vs[sr][vc0 + 8 + 2 * i]     = bf2f((unsigned short)(bw[i] & 0xffffu));
                vs[sr][vc0 + 8 + 2 * i + 1] = bf2f((unsigned short)(bw[i] >> 16));
            }
            const float2 pv = *(const float2*)(pbuf + ((size_t)b * KK + kk0 + sr) * HQ + h * Q + pq0);
            ps[sr][pq0]     = (pv.x + EPS) * invA;
            ps[sr][pq0 + 1] = (pv.y + EPS) * invB;
        }
        __syncthreads();
#pragma unroll 8
        for (int r = 0; r < 64; ++r) {
            const float vv = vs[r][d];
            acc0 = fmaf(ps[r][qg],     vv, acc0);
            acc1 = fmaf(ps[r][qg + 4], vv, acc1);
        }
    }
    upd[((size_t)b * Q + qg)     * D + h * DH + d] = acc0;
    upd[((size_t)b * Q + qg + 4) * D + h * DH + d] = acc1;
}

// K6: GRU cell + LN + MLP (residual). One block per (b,q) row. In-place slots.
__global__ __launch_bounds__(256) void k6_gru_mlp(
    const float* __restrict__ upd, float* __restrict__ slots,
    const float* __restrict__ WihT, const float* __restrict__ WhhT,
    const float* __restrict__ bih, const float* __restrict__ bhh,
    const float* __restrict__ lnw, const float* __restrict__ lnb,
    const float* __restrict__ W1, const float* __restrict__ b1,
    const float* __restrict__ W2, const float* __restrict__ b2)
{
    const int row = blockIdx.x, t = threadIdx.x;
    __shared__ float us[256], hs[256], ms[256], hid[512];
    __shared__ float red[8];
    us[t] = upd[(size_t)row * D + t];
    const float h0 = slots[(size_t)row * D + t];
    hs[t] = h0;
    __syncthreads();
    float a_r = bih[t], a_z = bih[256 + t], a_n = bih[512 + t];
    float c_r = bhh[t], c_z = bhh[256 + t], c_n = bhh[512 + t];
    for (int dd = 0; dd < 256; ++dd) {
        const float ud = us[dd], hd = hs[dd];
        const float* wi = WihT + (size_t)dd * 768;
        const float* wh = WhhT + (size_t)dd * 768;
        a_r = fmaf(ud, wi[t],       a_r);
        a_z = fmaf(ud, wi[256 + t], a_z);
        a_n = fmaf(ud, wi[512 + t], a_n);
        c_r = fmaf(hd, wh[t],       c_r);
        c_z = fmaf(hd, wh[256 + t], c_z);
        c_n = fmaf(hd, wh[512 + t], c_n);
    }
    const float r = 1.f / (1.f + __expf(-(a_r + c_r)));
    const float z = 1.f / (1.f + __expf(-(a_z + c_z)));
    const float n = tanhf(a_n + r * c_n);
    const float snew = (1.f - z) * n + z * h0;
    float mu, rs;
    {
        float s = snew, ss = snew * snew;
#pragma unroll
        for (int off = 32; off; off >>= 1) { s += __shfl_xor(s, off); ss += __shfl_xor(ss, off); }
        if ((t & 63) == 0) { red[t >> 6] = s; red[4 + (t >> 6)] = ss; }
        __syncthreads();
        const float S  = red[0] + red[1] + red[2] + red[3];
        const float SS = red[4] + red[5] + red[6] + red[7];
        mu = S * (1.f / 256.f);
        rs = rsqrtf(SS * (1.f / 256.f) - mu * mu + LNE);
    }
    ms[t] = (snew - mu) * rs * lnw[t] + lnb[t];
    __syncthreads();
    float g0 = b1[t], g1 = b1[256 + t];
    for (int dd = 0; dd < 256; ++dd) {
        const float md = ms[dd];
        g0 = fmaf(md, W1[(size_t)dd * HM + t],       g0);
        g1 = fmaf(md, W1[(size_t)dd * HM + 256 + t], g1);
    }
    hid[t]       = fmaxf(g0, 0.f);
    hid[256 + t] = fmaxf(g1, 0.f);
    __syncthreads();
    float o = b2[t];
    for (int j = 0; j < 512; ++j)
        o = fmaf(hid[j], W2[(size_t)j * D + t], o);
    slots[(size_t)row * D + t] = snew + o;
}

__global__ void k0_transpose768(const float* __restrict__ W, float* __restrict__ WT)
{
    const int i = blockIdx.x * 256 + threadIdx.x;  // over 768*256
    const int r = i >> 8, c = i & 255;
    WT[(size_t)c * 768 + r] = W[i];
}

__global__ void k7_copy(const float* __restrict__ s, float* __restrict__ o)
{
    const int i = blockIdx.x * 256 + threadIdx.x;
    o[i] = s[i];
}

// K7b: attn output [B,Q,K] = mean over h of (p+EPS)*invden
__global__ __launch_bounds__(256) void k7_attnout(
    const float* __restrict__ pbuf, const float* __restrict__ invden, float* __restrict__ out2)
{
    const int blk = blockIdx.x;
    const int b = blk >> 4;
    const int kk0 = (blk & 15) * 256;
    __shared__ float ps[256][33];
    __shared__ float inv[32];
    const int t = threadIdx.x;
    const float* pp = pbuf + ((size_t)b * KK + kk0) * HQ;
    for (int i = 0; i < 32; ++i) {
        const int idx = i * 256 + t;
        ps[idx >> 5][idx & 31] = pp[idx];
    }
    if (t < 32) inv[t] = invden[b * HQ + t];
    __syncthreads();
    float* o = out2 + (size_t)b * Q * KK + kk0 + t;
#pragma unroll
    for (int q = 0; q < 8; ++q) {
        float v = 0.f;
#pragma unroll
        for (int hh = 0; hh < 4; ++hh)
            v += (ps[t][hh * 8 + q] + EPS) * inv[hh * 8 + q];
        o[(size_t)q * KK] = v * 0.25f;
    }
}

extern "C" void kernel_launch(void* const* d_in, const int* in_sizes, int n_in,
                              void* d_out, int out_size, void* d_ws, size_t ws_size,
                              hipStream_t stream)
{
    const float* inputs  = (const float*)d_in[0];
    const float* slots0  = (const float*)d_in[1];
    const float* Wq      = (const float*)d_in[2];
    const float* Wk      = (const float*)d_in[3];
    const float* Wv      = (const float*)d_in[4];
    const float* ln_in_w = (const float*)d_in[5];
    const float* ln_in_b = (const float*)d_in[6];
    const float* ln_s_w  = (const float*)d_in[7];
    const float* ln_s_b  = (const float*)d_in[8];
    const float* ln_m_w  = (const float*)d_in[9];
    const float* ln_m_b  = (const float*)d_in[10];
    const float* gWih    = (const float*)d_in[11];
    const float* gWhh    = (const float*)d_in[12];
    const float* gbih    = (const float*)d_in[13];
    const float* gbhh    = (const float*)d_in[14];
    const float* W1      = (const float*)d_in[15];
    const float* b1      = (const float*)d_in[16];
    const float* W2      = (const float*)d_in[17];
    const float* b2      = (const float*)d_in[18];

    char* ws = (char*)d_ws;
    unsigned short* kbuf = (unsigned short*)ws; ws += (size_t)B * KK * D * 2;
    unsigned short* vbuf = (unsigned short*)ws; ws += (size_t)B * KK * D * 2;
    float* pbuf   = (float*)ws; ws += (size_t)B * KK * HQ * 4;
    float* invden = (float*)ws; ws += (size_t)B * HQ * 4;
    float* qbuf   = (float*)ws; ws += (size_t)B * Q * D * 4;
    float* slots  = (float*)ws; ws += (size_t)B * Q * D * 4;
    float* upd    = (float*)ws; ws += (size_t)B * Q * D * 4;
    float* WihT   = (float*)ws; ws += (size_t)768 * 256 * 4;
    float* WhhT   = (float*)ws; ws += (size_t)768 * 256 * 4;
    // total ws used: ~305.2 MB

    hipMemcpyAsync(slots, slots0, (size_t)B * Q * D * 4, hipMemcpyDeviceToDevice, stream);
    k0_transpose768<<<768, 256, 0, stream>>>(gWih, WihT);
    k0_transpose768<<<768, 256, 0, stream>>>(gWhh, WhhT);
    k1_ln_kvproj<<<(B * KK) / 32, 256, 0, stream>>>(inputs, Wk, Wv, ln_in_w, ln_in_b, kbuf, vbuf);
    for (int it = 0; it < 3; ++it) {
        k2_qproj<<<B * Q, 256, 0, stream>>>(slots, Wq, ln_s_w, ln_s_b, qbuf);
        k3_logits<<<B * (KK / 4), 256, 0, stream>>>(kbuf, qbuf, pbuf);
        k4_sums<<<B, 1024, 0, stream>>>(pbuf, invden);
        k5_updates<<<B * H, 256, 0, stream>>>(pbuf, vbuf, invden, upd);
        k6_gru_mlp<<<B * Q, 256, 0, stream>>>(upd, slots, WihT, WhhT, gbih, gbhh,
                                              ln_m_w, ln_m_b, W1, b1, W2, b2);
    }
    k7_copy<<<(B * Q * D) / 256, 256, 0, stream>>>(slots, (float*)d_out);
    k7_attnout<<<B * (KK / 256), 256, 0, stream>>>(pbuf, invden, (float*)d_out + (size_t)B * Q * D);
}

// Round 2
// 1240.906 us; speedup vs baseline: 1.6027x; 1.6027x over previous
//
#include <hip/hip_runtime.h>

#define B   64
#define KK  4096
#define D   256
#define Q   8
#define H   4
#define DH  64
#define HQ  32
#define HM  512
#define EPS 1e-8f
#define LNE 1e-5f
#define SCALE 0.125f

typedef short bf16x8 __attribute__((ext_vector_type(8)));
typedef float f32x4 __attribute__((ext_vector_type(4)));

__device__ __forceinline__ float bf2f(unsigned short u) {
    unsigned int x = ((unsigned int)u) << 16;
    float f; __builtin_memcpy(&f, &x, 4); return f;
}
__device__ __forceinline__ unsigned short f2bf(float f) {
    unsigned int x; __builtin_memcpy(&x, &f, 4);
    unsigned int lsb = (x >> 16) & 1u;
    x += 0x7fffu + lsb;
    return (unsigned short)(x >> 16);
}

// K0b: WkvT[c][d] = bf16( c<256 ? Wk[d][c]*SCALE : Wv[d][c-256] ). [512][256] bf16.
__global__ __launch_bounds__(256) void k0_wkv(
    const float* __restrict__ Wk, const float* __restrict__ Wv,
    unsigned short* __restrict__ WkvT)
{
    const int c = blockIdx.x, d = threadIdx.x;
    const float v = (c < 256) ? Wk[(size_t)d * 256 + c] * SCALE
                              : Wv[(size_t)d * 256 + (c - 256)];
    WkvT[(size_t)c * 256 + d] = f2bf(v);
}

// K1: fused LN(inputs) + [k*scale | v] = xhat @ WkvT^T via bf16 MFMA.
// BM=64 rows/block, full K=256, N-loop over 8 x 64-col tiles of WkvT.
__global__ __launch_bounds__(256) void k1_mfma(
    const float* __restrict__ inp, const unsigned short* __restrict__ WkvT,
    const float* __restrict__ lnw, const float* __restrict__ lnb,
    unsigned short* __restrict__ kbuf, unsigned short* __restrict__ vbuf)
{
    __shared__ unsigned short As[64 * 256];   // 32 KB, rows 512B, XOR-swizzled
    __shared__ unsigned short Bs[64 * 256];   // 32 KB
    char* abase = (char*)As;
    char* bbase = (char*)Bs;
    const int t = threadIdx.x;
    const int w = t >> 6, l = t & 63;
    const size_t row0 = (size_t)blockIdx.x * 64;

    // ---- stage A: LN rows -> bf16, swizzled LDS (wave-local rows w*16..w*16+15)
    const float4 w4 = ((const float4*)lnw)[l];
    const float4 b4 = ((const float4*)lnb)[l];
#pragma unroll
    for (int i = 0; i < 16; ++i) {
        const int r = w * 16 + i;
        float4 xv = ((const float4*)(inp + (row0 + r) * D))[l];
        float s  = xv.x + xv.y + xv.z + xv.w;
        float ss = xv.x*xv.x + xv.y*xv.y + xv.z*xv.z + xv.w*xv.w;
#pragma unroll
        for (int off = 32; off; off >>= 1) { s += __shfl_xor(s, off); ss += __shfl_xor(ss, off); }
        const float mu = s * (1.f / 256.f);
        const float rs = rsqrtf(ss * (1.f / 256.f) - mu * mu + LNE);
        ushort4 p;
        p.x = f2bf((xv.x - mu) * rs * w4.x + b4.x);
        p.y = f2bf((xv.y - mu) * rs * w4.y + b4.y);
        p.z = f2bf((xv.z - mu) * rs * w4.z + b4.z);
        p.w = f2bf((xv.w - mu) * rs * w4.w + b4.w);
        *(ushort4*)(abase + r * 512 + ((l * 8) ^ ((r & 7) << 4))) = p;
    }
    __syncthreads();

    // ---- hoist A fragments (wave w owns output rows w*16..w*16+15)
    // A[m][k]: lane holds m = w*16 + (l&15), k = kk*32 + (l>>4)*8 + j
    const int arow = w * 16 + (l & 15);
    const char* ap = abase + arow * 512;
    const int asw = (l & 7) << 4;
    bf16x8 afrag[8];
#pragma unroll
    for (int kk = 0; kk < 8; ++kk)
        afrag[kk] = *(const bf16x8*)(ap + ((kk * 64 + (l >> 4) * 16) ^ asw));

    // ---- N-loop: 8 tiles of 64 output columns
    for (int n = 0; n < 8; ++n) {
        const int c0 = n * 64;
        if (n) __syncthreads();   // previous tile's reads done before overwrite
        // stage B: Bs[localcol][k], wave w stages local cols w*16..w*16+15
        const unsigned short* gB = WkvT + (size_t)(c0 + w * 16) * 256;
#pragma unroll
        for (int i = 0; i < 16; ++i) {
            const int r = w * 16 + i;
            const ushort4 u = *(const ushort4*)(gB + (size_t)i * 256 + l * 4);
            *(ushort4*)(bbase + r * 512 + ((l * 8) ^ ((r & 7) << 4))) = u;
        }
        __syncthreads();

        f32x4 acc[4] = {{0.f,0.f,0.f,0.f},{0.f,0.f,0.f,0.f},{0.f,0.f,0.f,0.f},{0.f,0.f,0.f,0.f}};
#pragma unroll
        for (int kk = 0; kk < 8; ++kk) {
            const int koff = kk * 64 + (l >> 4) * 16;
#pragma unroll
            for (int nf = 0; nf < 4; ++nf) {
                const int brow = nf * 16 + (l & 15);
                const bf16x8 bfrag = *(const bf16x8*)(bbase + brow * 512 + (koff ^ ((brow & 7) << 4)));
                acc[nf] = __builtin_amdgcn_mfma_f32_16x16x32_bf16(afrag[kk], bfrag, acc[nf], 0, 0, 0);
            }
        }

        // epilogue: D[m][c], c = lane&15 (+16*nf+c0), m = (lane>>4)*4+reg (+w*16)
#pragma unroll
        for (int nf = 0; nf < 4; ++nf) {
            const int c = c0 + nf * 16 + (l & 15);
            unsigned short* op = (c < 256) ? kbuf : vbuf;
            const int cc = (c < 256) ? c : c - 256;
#pragma unroll
            for (int reg = 0; reg < 4; ++reg) {
                const size_t grow = row0 + w * 16 + (l >> 4) * 4 + reg;
                op[grow * 256 + cc] = f2bf(acc[nf][reg]);
            }
        }
    }
}

// K2: LN(slots) + q = s_n @ Wq. One block per (b,q) row.
__global__ __launch_bounds__(256) void k2_qproj(
    const float* __restrict__ slots, const float* __restrict__ Wq,
    const float* __restrict__ lnw, const float* __restrict__ lnb, float* __restrict__ qbuf)
{
    const int row = blockIdx.x, t = threadIdx.x;
    __shared__ float sn[256];
    __shared__ float red[8];
    const float x = slots[(size_t)row * D + t];
    float mu, rs;
    {
        float s = x, ss = x * x;
#pragma unroll
        for (int off = 32; off; off >>= 1) { s += __shfl_xor(s, off); ss += __shfl_xor(ss, off); }
        if ((t & 63) == 0) { red[t >> 6] = s; red[4 + (t >> 6)] = ss; }
        __syncthreads();
        const float S  = red[0] + red[1] + red[2] + red[3];
        const float SS = red[4] + red[5] + red[6] + red[7];
        mu = S * (1.f / 256.f);
        rs = rsqrtf(SS * (1.f / 256.f) - mu * mu + LNE);
    }
    sn[t] = (x - mu) * rs * lnw[t] + lnb[t];
    __syncthreads();
    float acc = 0.f;
    for (int d = 0; d < 256; ++d) acc = fmaf(sn[d], Wq[(size_t)d * 256 + t], acc);
    qbuf[(size_t)row * D + t] = acc;
}

// K3: logits (k . q) + joint softmax over H*Q=32 per (b,kk). One wave per kk row.
__global__ __launch_bounds__(256) void k3_logits(
    const unsigned short* __restrict__ kbuf, const float* __restrict__ qbuf,
    float* __restrict__ pbuf)
{
    const int blk = blockIdx.x;
    const int b = blk >> 10;
    const int kk0 = (blk & 1023) * 4;
    __shared__ float qs[2048];
    __shared__ float ks[4][256];
    const int t = threadIdx.x;
    {
        const float4* q4 = (const float4*)(qbuf + (size_t)b * (Q * D));
        float4* qs4 = (float4*)qs;
        qs4[t] = q4[t];
        qs4[256 + t] = q4[256 + t];
        const ushort4* kp = (const ushort4*)(kbuf + ((size_t)b * KK + kk0) * D);
        const ushort4 u = kp[t];
        const int r = t >> 6, c0 = (t & 63) * 4;
        ks[r][c0 + 0] = bf2f(u.x); ks[r][c0 + 1] = bf2f(u.y);
        ks[r][c0 + 2] = bf2f(u.z); ks[r][c0 + 3] = bf2f(u.w);
    }
    __syncthreads();
    const int wv = t >> 6, lane = t & 63;
    const int hq = lane & 31, h = hq >> 3, q = hq & 7;
    const int half = lane >> 5;
    const float* qrow = qs + q * 256 + h * 64 + half * 32;
    const float* krow = &ks[wv][h * 64 + half * 32];
    float acc = 0.f;
#pragma unroll
    for (int i = 0; i < 32; ++i) {
        const int d = (i + lane) & 31;
        acc = fmaf(krow[d], qrow[d], acc);
    }
    acc += __shfl_xor(acc, 32);
    float m = acc;
#pragma unroll
    for (int off = 16; off; off >>= 1) m = fmaxf(m, __shfl_xor(m, off));
    const float e = __expf(acc - m);
    float se = e;
#pragma unroll
    for (int off = 16; off; off >>= 1) se += __shfl_xor(se, off);
    const float p = e / se;
    if (lane < 32)
        pbuf[((size_t)b * KK + kk0 + wv) * HQ + hq] = p;
}

// K4: denominator per (b,h,q): 1 / (sum_k p + K*EPS)
__global__ __launch_bounds__(1024) void k4_sums(
    const float* __restrict__ pbuf, float* __restrict__ invden)
{
    const int b = blockIdx.x, t = threadIdx.x;
    const int hq = t & 31, g = t >> 5;
    const float* pb = pbuf + (size_t)b * KK * HQ;
    float acc = 0.f;
    for (int kk = g; kk < KK; kk += 32)
        acc += pb[(size_t)kk * HQ + hq];
    __shared__ float red[1024];
    red[t] = acc;
    __syncthreads();
    for (int s = 512; s >= 32; s >>= 1) {
        if (t < s) red[t] += red[t + s];
        __syncthreads();
    }
    if (t < 32) invden[b * HQ + t] = 1.f / (red[t] + (float)KK * EPS);
}

// K5: updates[b,q,h*64+d] = sum_k attn_final * v. One block per (b,h).
__global__ __launch_bounds__(256) void k5_updates(
    const float* __restrict__ pbuf, const unsigned short* __restrict__ vbuf,
    const float* __restrict__ invden, float* __restrict__ upd)
{
    const int blk = blockIdx.x;
    const int b = blk >> 2, h = blk & 3;
    const int t = threadIdx.x;
    __shared__ float vs[64][64];
    __shared__ float ps[64][8];
    const int d = t & 63, qg = t >> 6;
    const int sr = t >> 2;
    const int vc0 = (t & 3) * 16;
    const int pq0 = (t & 3) * 2;
    const float invA = invden[b * HQ + h * Q + pq0];
    const float invB = invden[b * HQ + h * Q + pq0 + 1];
    float acc0 = 0.f, acc1 = 0.f;
    for (int kk0 = 0; kk0 < KK; kk0 += 64) {
        __syncthreads();
        {
            const unsigned short* vp = vbuf + (((size_t)b * KK + kk0 + sr) * D + h * DH + vc0);
            const uint4 A  = *(const uint4*)vp;
            const uint4 Bq = *(const uint4*)(vp + 8);
            const unsigned int aw[4] = {A.x, A.y, A.z, A.w};
            const unsigned int bw[4] = {Bq.x, Bq.y, Bq.z, Bq.w};
#pragma unroll
            for (int i = 0; i < 4; ++i) {
                vs[sr][vc0 + 2 * i]         = bf2f((unsigned short)(aw[i] & 0xffffu));
                vs[sr][vc0 + 2 * i + 1]     = bf2f((unsigned short)(aw[i] >> 16));
                vs[sr][vc0 + 8 + 2 * i]     = bf2f((unsigned short)(bw[i] & 0xffffu));
                vs[sr][vc0 + 8 + 2 * i + 1] = bf2f((unsigned short)(bw[i] >> 16));
            }
            const float2 pv = *(const float2*)(pbuf + ((size_t)b * KK + kk0 + sr) * HQ + h * Q + pq0);
            ps[sr][pq0]     = (pv.x + EPS) * invA;
            ps[sr][pq0 + 1] = (pv.y + EPS) * invB;
        }
        __syncthreads();
#pragma unroll 8
        for (int r = 0; r < 64; ++r) {
            const float vv = vs[r][d];
            acc0 = fmaf(ps[r][qg],     vv, acc0);
            acc1 = fmaf(ps[r][qg + 4], vv, acc1);
        }
    }
    upd[((size_t)b * Q + qg)     * D + h * DH + d] = acc0;
    upd[((size_t)b * Q + qg + 4) * D + h * DH + d] = acc1;
}

// K6: GRU cell + LN + MLP (residual). One block per (b,q) row. In-place slots.
__global__ __launch_bounds__(256) void k6_gru_mlp(
    const float* __restrict__ upd, float* __restrict__ slots,
    const float* __restrict__ WihT, const float* __restrict__ WhhT,
    const float* __restrict__ bih, const float* __restrict__ bhh,
    const float* __restrict__ lnw, const float* __restrict__ lnb,
    const float* __restrict__ W1, const float* __restrict__ b1,
    const float* __restrict__ W2, const float* __restrict__ b2)
{
    const int row = blockIdx.x, t = threadIdx.x;
    __shared__ float us[256], hs[256], ms[256], hid[512];
    __shared__ float red[8];
    us[t] = upd[(size_t)row * D + t];
    const float h0 = slots[(size_t)row * D + t];
    hs[t] = h0;
    __syncthreads();
    float a_r = bih[t], a_z = bih[256 + t], a_n = bih[512 + t];
    float c_r = bhh[t], c_z = bhh[256 + t], c_n = bhh[512 + t];
    for (int dd = 0; dd < 256; ++dd) {
        const float ud = us[dd], hd = hs[dd];
        const float* wi = WihT + (size_t)dd * 768;
        const float* wh = WhhT + (size_t)dd * 768;
        a_r = fmaf(ud, wi[t],       a_r);
        a_z = fmaf(ud, wi[256 + t], a_z);
        a_n = fmaf(ud, wi[512 + t], a_n);
        c_r = fmaf(hd, wh[t],       c_r);
        c_z = fmaf(hd, wh[256 + t], c_z);
        c_n = fmaf(hd, wh[512 + t], c_n);
    }
    const float r = 1.f / (1.f + __expf(-(a_r + c_r)));
    const float z = 1.f / (1.f + __expf(-(a_z + c_z)));
    const float n = tanhf(a_n + r * c_n);
    const float snew = (1.f - z) * n + z * h0;
    float mu, rs;
    {
        float s = snew, ss = snew * snew;
#pragma unroll
        for (int off = 32; off; off >>= 1) { s += __shfl_xor(s, off); ss += __shfl_xor(ss, off); }
        if ((t & 63) == 0) { red[t >> 6] = s; red[4 + (t >> 6)] = ss; }
        __syncthreads();
        const float S  = red[0] + red[1] + red[2] + red[3];
        const float SS = red[4] + red[5] + red[6] + red[7];
        mu = S * (1.f / 256.f);
        rs = rsqrtf(SS * (1.f / 256.f) - mu * mu + LNE);
    }
    ms[t] = (snew - mu) * rs * lnw[t] + lnb[t];
    __syncthreads();
    float g0 = b1[t], g1 = b1[256 + t];
    for (int dd = 0; dd < 256; ++dd) {
        const float md = ms[dd];
        g0 = fmaf(md, W1[(size_t)dd * HM + t],       g0);
        g1 = fmaf(md, W1[(size_t)dd * HM + 256 + t], g1);
    }
    hid[t]       = fmaxf(g0, 0.f);
    hid[256 + t] = fmaxf(g1, 0.f);
    __syncthreads();
    float o = b2[t];
    for (int j = 0; j < 512; ++j)
        o = fmaf(hid[j], W2[(size_t)j * D + t], o);
    slots[(size_t)row * D + t] = snew + o;
}

__global__ void k0_transpose768(const float* __restrict__ W, float* __restrict__ WT)
{
    const int i = blockIdx.x * 256 + threadIdx.x;  // over 768*256
    const int r = i >> 8, c = i & 255;
    WT[(size_t)c * 768 + r] = W[i];
}

__global__ void k7_copy(const float* __restrict__ s, float* __restrict__ o)
{
    const int i = blockIdx.x * 256 + threadIdx.x;
    o[i] = s[i];
}

// K7b: attn output [B,Q,K] = mean over h of (p+EPS)*invden
__global__ __launch_bounds__(256) void k7_attnout(
    const float* __restrict__ pbuf, const float* __restrict__ invden, float* __restrict__ out2)
{
    const int blk = blockIdx.x;
    const int b = blk >> 4;
    const int kk0 = (blk & 15) * 256;
    __shared__ float ps[256][33];
    __shared__ float inv[32];
    const int t = threadIdx.x;
    const float* pp = pbuf + ((size_t)b * KK + kk0) * HQ;
    for (int i = 0; i < 32; ++i) {
        const int idx = i * 256 + t;
        ps[idx >> 5][idx & 31] = pp[idx];
    }
    if (t < 32) inv[t] = invden[b * HQ + t];
    __syncthreads();
    float* o = out2 + (size_t)b * Q * KK + kk0 + t;
#pragma unroll
    for (int q = 0; q < 8; ++q) {
        float v = 0.f;
#pragma unroll
        for (int hh = 0; hh < 4; ++hh)
            v += (ps[t][hh * 8 + q] + EPS) * inv[hh * 8 + q];
        o[(size_t)q * KK] = v * 0.25f;
    }
}

extern "C" void kernel_launch(void* const* d_in, const int* in_sizes, int n_in,
                              void* d_out, int out_size, void* d_ws, size_t ws_size,
                              hipStream_t stream)
{
    const float* inputs  = (const float*)d_in[0];
    const float* slots0  = (const float*)d_in[1];
    const float* Wq      = (const float*)d_in[2];
    const float* Wk      = (const float*)d_in[3];
    const float* Wv      = (const float*)d_in[4];
    const float* ln_in_w = (const float*)d_in[5];
    const float* ln_in_b = (const float*)d_in[6];
    const float* ln_s_w  = (const float*)d_in[7];
    const float* ln_s_b  = (const float*)d_in[8];
    const float* ln_m_w  = (const float*)d_in[9];
    const float* ln_m_b  = (const float*)d_in[10];
    const float* gWih    = (const float*)d_in[11];
    const float* gWhh    = (const float*)d_in[12];
    const float* gbih    = (const float*)d_in[13];
    const float* gbhh    = (const float*)d_in[14];
    const float* W1      = (const float*)d_in[15];
    const float* b1      = (const float*)d_in[16];
    const float* W2      = (const float*)d_in[17];
    const float* b2      = (const float*)d_in[18];

    char* ws = (char*)d_ws;
    unsigned short* kbuf = (unsigned short*)ws; ws += (size_t)B * KK * D * 2;
    unsigned short* vbuf = (unsigned short*)ws; ws += (size_t)B * KK * D * 2;
    float* pbuf   = (float*)ws; ws += (size_t)B * KK * HQ * 4;
    float* invden = (float*)ws; ws += (size_t)B * HQ * 4;
    float* qbuf   = (float*)ws; ws += (size_t)B * Q * D * 4;
    float* slots  = (float*)ws; ws += (size_t)B * Q * D * 4;
    float* upd    = (float*)ws; ws += (size_t)B * Q * D * 4;
    float* WihT   = (float*)ws; ws += (size_t)768 * 256 * 4;
    float* WhhT   = (float*)ws; ws += (size_t)768 * 256 * 4;
    unsigned short* WkvT = (unsigned short*)ws; ws += (size_t)512 * 256 * 2;
    // total ws used: ~305.5 MB

    hipMemcpyAsync(slots, slots0, (size_t)B * Q * D * 4, hipMemcpyDeviceToDevice, stream);
    k0_transpose768<<<768, 256, 0, stream>>>(gWih, WihT);
    k0_transpose768<<<768, 256, 0, stream>>>(gWhh, WhhT);
    k0_wkv<<<512, 256, 0, stream>>>(Wk, Wv, WkvT);
    k1_mfma<<<(B * KK) / 64, 256, 0, stream>>>(inputs, WkvT, ln_in_w, ln_in_b, kbuf, vbuf);
    for (int it = 0; it < 3; ++it) {
        k2_qproj<<<B * Q, 256, 0, stream>>>(slots, Wq, ln_s_w, ln_s_b, qbuf);
        k3_logits<<<B * (KK / 4), 256, 0, stream>>>(kbuf, qbuf, pbuf);
        k4_sums<<<B, 1024, 0, stream>>>(pbuf, invden);
        k5_updates<<<B * H, 256, 0, stream>>>(pbuf, vbuf, invden, upd);
        k6_gru_mlp<<<B * Q, 256, 0, stream>>>(upd, slots, WihT, WhhT, gbih, gbhh,
                                              ln_m_w, ln_m_b, W1, b1, W2, b2);
    }
    k7_copy<<<(B * Q * D) / 256, 256, 0, stream>>>(slots, (float*)d_out);
    k7_attnout<<<B * (KK / 256), 256, 0, stream>>>(pbuf, invden, (float*)d_out + (size_t)B * Q * D);
}

// Round 3
// 464.249 us; speedup vs baseline: 4.2840x; 2.6729x over previous
//
#include <hip/hip_runtime.h>

#define B   64
#define KK  4096
#define D   256
#define Q   8
#define H   4
#define DH  64
#define HQ  32
#define HM  512
#define NCH 8
#define CHK 512
#define EPS 1e-8f
#define LNE 1e-5f
#define SCALE 0.125f

typedef short bf16x8 __attribute__((ext_vector_type(8)));
typedef float f32x4 __attribute__((ext_vector_type(4)));

__device__ __forceinline__ float bf2f(unsigned short u) {
    unsigned int x = ((unsigned int)u) << 16;
    float f; __builtin_memcpy(&f, &x, 4); return f;
}
__device__ __forceinline__ unsigned short f2bf(float f) {
    unsigned int x; __builtin_memcpy(&x, &f, 4);
    unsigned int lsb = (x >> 16) & 1u;
    x += 0x7fffu + lsb;
    return (unsigned short)(x >> 16);
}

__device__ __forceinline__ void gload16(const void* g, void* l) {
    __builtin_amdgcn_global_load_lds(
        (const __attribute__((address_space(1))) unsigned int*)g,
        (__attribute__((address_space(3))) unsigned int*)l, 16, 0, 0);
}

// stage a [64 rows x 512B] bf16 tile into LDS, XOR-swizzled ((r&7)<<4), via
// global_load_lds with pre-swizzled source. 8 issues/wave, 2 rows per 1KB seg.
__device__ __forceinline__ void stage64x512B(const char* src, size_t row0,
                                             size_t stride, char* lds, int w, int l)
{
#pragma unroll
    for (int i = 0; i < 8; ++i) {
        const int seg = w * 8 + i;
        const int r = seg * 2 + (l >> 5);
        const int off = ((l & 31) * 16) ^ ((r & 7) << 4);
        gload16(src + (row0 + r) * stride + off, lds + seg * 1024);
    }
}

// ---------------- prep kernels ----------------
__global__ void k_init(const float* __restrict__ s0, float* __restrict__ slots,
                       unsigned short* __restrict__ slots_bf)
{
    const int i = blockIdx.x * 256 + threadIdx.x;
    const float v = s0[i];
    slots[i] = v; slots_bf[i] = f2bf(v);
}

__global__ __launch_bounds__(256) void k0_wkv(
    const float* __restrict__ Wk, const float* __restrict__ Wv,
    unsigned short* __restrict__ WkvT)
{
    const int c = blockIdx.x, d = threadIdx.x;
    const float v = (c < 256) ? Wk[(size_t)d * 256 + c] * SCALE
                              : Wv[(size_t)d * 256 + (c - 256)];
    WkvT[(size_t)c * 256 + d] = f2bf(v);
}

__global__ void k0_cvt(const float* __restrict__ src, unsigned short* __restrict__ dst)
{
    const int i = blockIdx.x * 256 + threadIdx.x;
    dst[i] = f2bf(src[i]);
}

__global__ void k0_t1(const float* __restrict__ W1, unsigned short* __restrict__ W1T)
{   // [256][512] -> bf16 [512][256]
    const int n = blockIdx.x, d = threadIdx.x;
    W1T[(size_t)n * 256 + d] = f2bf(W1[(size_t)d * 512 + n]);
}

__global__ void k0_t2(const float* __restrict__ W2, unsigned short* __restrict__ W2T)
{   // [512][256] -> bf16 [256][512]
    const int n = blockIdx.x, j = threadIdx.x;
    W2T[(size_t)n * 512 + j]       = f2bf(W2[(size_t)j * 256 + n]);
    W2T[(size_t)n * 512 + 256 + j] = f2bf(W2[(size_t)(256 + j) * 256 + n]);
}

// ---------------- K1: LN + K/V projection (MFMA, dbuf B) ----------------
__global__ __launch_bounds__(256) void k1_mfma(
    const float* __restrict__ inp, const unsigned short* __restrict__ WkvT,
    const float* __restrict__ lnw, const float* __restrict__ lnb,
    unsigned short* __restrict__ kbuf, unsigned short* __restrict__ vbufT)
{
    __shared__ char smem[65536];
    char* abase = smem;
    char* bb0 = smem + 32768;      // buf0
    char* bb1 = smem;              // buf1 reuses A region after frag hoist
    const int t = threadIdx.x, w = t >> 6, l = t & 63;
    const size_t row0 = (size_t)blockIdx.x * 64;

    // load all 16 rows upfront (outstanding HBM loads), then LN each
    float4 xv[16];
#pragma unroll
    for (int i = 0; i < 16; ++i)
        xv[i] = ((const float4*)(inp + (row0 + w * 16 + i) * D))[l];
    const float4 w4 = ((const float4*)lnw)[l];
    const float4 b4 = ((const float4*)lnb)[l];
#pragma unroll
    for (int i = 0; i < 16; ++i) {
        const int r = w * 16 + i;
        float4 x = xv[i];
        float s  = x.x + x.y + x.z + x.w;
        float ss = x.x*x.x + x.y*x.y + x.z*x.z + x.w*x.w;
#pragma unroll
        for (int off = 32; off; off >>= 1) { s += __shfl_xor(s, off); ss += __shfl_xor(ss, off); }
        const float mu = s * (1.f / 256.f);
        const float rs = rsqrtf(ss * (1.f / 256.f) - mu * mu + LNE);
        ushort4 pk;
        pk.x = f2bf((x.x - mu) * rs * w4.x + b4.x);
        pk.y = f2bf((x.y - mu) * rs * w4.y + b4.y);
        pk.z = f2bf((x.z - mu) * rs * w4.z + b4.z);
        pk.w = f2bf((x.w - mu) * rs * w4.w + b4.w);
        *(ushort4*)(abase + r * 512 + ((l * 8) ^ ((r & 7) << 4))) = pk;
    }
    __syncthreads();

    // hoist A fragments
    const int arow = w * 16 + (l & 15);
    const char* ap = abase + arow * 512;
    const int asw = (l & 7) << 4;
    bf16x8 af[8];
#pragma unroll
    for (int kk = 0; kk < 8; ++kk)
        af[kk] = *(const bf16x8*)(ap + ((kk * 64 + (l >> 4) * 16) ^ asw));

    stage64x512B((const char*)WkvT, 0, 512, bb0, w, l);
    __syncthreads();   // B0 ready; all hoists done

    const f32x4 fz = {0.f, 0.f, 0.f, 0.f};
    for (int n2 = 0; n2 < 8; ++n2) {
        if (n2 < 7)
            stage64x512B((const char*)WkvT, (size_t)(n2 + 1) * 64, 512,
                         ((n2 + 1) & 1) ? bb1 : bb0, w, l);
        const char* bbase = (n2 & 1) ? bb1 : bb0;
        f32x4 acc[4] = {fz, fz, fz, fz};
#pragma unroll
        for (int kk = 0; kk < 8; ++kk) {
            const int koff = kk * 64 + (l >> 4) * 16;
#pragma unroll
            for (int nf = 0; nf < 4; ++nf) {
                const int brow = nf * 16 + (l & 15);
                const bf16x8 bf_ = *(const bf16x8*)(bbase + brow * 512 + (koff ^ ((brow & 7) << 4)));
                acc[nf] = __builtin_amdgcn_mfma_f32_16x16x32_bf16(af[kk], bf_, acc[nf], 0, 0, 0);
            }
        }
        const int c0 = n2 * 64;
        const size_t grow0 = row0 + w * 16 + (l >> 4) * 4;
#pragma unroll
        for (int nf = 0; nf < 4; ++nf) {
            const int c = c0 + nf * 16 + (l & 15);
            if (c < 256) {
#pragma unroll
                for (int reg = 0; reg < 4; ++reg)
                    kbuf[(grow0 + reg) * 256 + c] = f2bf(acc[nf][reg]);
            } else {
                const int cc = c - 256;
                const size_t bb = grow0 >> 12;
                const int kl = (int)(grow0 & 4095);
                ushort4 pk;
                pk.x = f2bf(acc[nf][0]); pk.y = f2bf(acc[nf][1]);
                pk.z = f2bf(acc[nf][2]); pk.w = f2bf(acc[nf][3]);
                *(ushort4*)(vbufT + ((bb * 256 + cc) * KK + kl)) = pk;
            }
        }
        __syncthreads();
    }
}

// ---------------- K2: LN(slots) + q projection ----------------
__global__ __launch_bounds__(256) void k2_qproj(
    const float* __restrict__ slots, const float* __restrict__ Wq,
    const float* __restrict__ lnw, const float* __restrict__ lnb, float* __restrict__ qbuf)
{
    const int row = blockIdx.x, t = threadIdx.x;
    __shared__ float sn[256];
    __shared__ float red[8];
    const float x = slots[(size_t)row * D + t];
    float mu, rs;
    {
        float s = x, ss = x * x;
#pragma unroll
        for (int off = 32; off; off >>= 1) { s += __shfl_xor(s, off); ss += __shfl_xor(ss, off); }
        if ((t & 63) == 0) { red[t >> 6] = s; red[4 + (t >> 6)] = ss; }
        __syncthreads();
        const float S  = red[0] + red[1] + red[2] + red[3];
        const float SS = red[4] + red[5] + red[6] + red[7];
        mu = S * (1.f / 256.f);
        rs = rsqrtf(SS * (1.f / 256.f) - mu * mu + LNE);
    }
    sn[t] = (x - mu) * rs * lnw[t] + lnb[t];
    __syncthreads();
    float acc = 0.f;
    for (int d = 0; d < 256; ++d) acc = fmaf(sn[d], Wq[(size_t)d * 256 + t], acc);
    qbuf[(size_t)row * D + t] = acc;
}

// ---------------- fused attention: logits + joint softmax + PV ----------------
// grid = B*NCH blocks; per block: 512 k-rows in 8 tiles of 64.
__global__ __launch_bounds__(256) void k_attn(
    const unsigned short* __restrict__ kbuf, const unsigned short* __restrict__ vbufT,
    const float* __restrict__ qbuf, float* __restrict__ updp,
    float* __restrict__ denp, float* __restrict__ pbuf, int write_p)
{
    __shared__ unsigned short ksm[64 * 256];   // K tile [64 k][256 d], 512B rows, swizzled
    __shared__ unsigned short vsm[256 * 64];   // V^T tile [256 d][64 k], 128B rows, swizzled
    __shared__ unsigned short psm[32 * 64];    // P^T [32 hq][64 k], 128B rows, swizzled
    __shared__ float dred[4][32];
    const int t = threadIdx.x, w = t >> 6, l = t & 63;
    const int b = blockIdx.x >> 3, chunk = blockIdx.x & 7;
    const int k0g = chunk * CHK;
    const int n = l & 15, lg = l >> 4;

    // ---- stage tile 0
    auto stage_ks = [&](int tile) {
        const size_t rowg = (size_t)b * KK + k0g + tile * 64;
#pragma unroll
        for (int i = 0; i < 8; ++i) {
            const int seg = w * 8 + i;
            const int r = seg * 2 + (l >> 5);
            const int off = ((l & 31) * 16) ^ ((r & 7) << 4);
            gload16((const char*)kbuf + (rowg + r) * 512 + off, (char*)ksm + seg * 1024);
        }
    };
    auto stage_vs = [&](int tile) {
        const int kk0 = k0g + tile * 64;
#pragma unroll
        for (int i = 0; i < 8; ++i) {
            const int seg = w * 8 + i;
            const int d = seg * 8 + (l >> 3);
            const int off = ((l & 7) * 16) ^ ((d & 7) << 4);
            gload16((const char*)vbufT + (((size_t)b * 256 + d) * KK + kk0) * 2 + off,
                    (char*)vsm + seg * 1024);
        }
    };
    stage_ks(0); stage_vs(0);

    // ---- q fragments in registers (block-diagonal Q32)
    bf16x8 qf[2][2];
#pragma unroll
    for (int p = 0; p < 2; ++p) {
        const int h = p * 2 + (n >> 3);
        const float* qb = qbuf + ((size_t)b * Q + (n & 7)) * D;
#pragma unroll
        for (int j = 0; j < 2; ++j) {
            const int dbase = (h * 2 + j) * 32 + lg * 8;
            short tmp[8];
#pragma unroll
            for (int e = 0; e < 8; ++e) tmp[e] = (short)f2bf(qb[dbase + e]);
            __builtin_memcpy(&qf[p][j], tmp, 16);
        }
    }
    const bf16x8 ZV = {0,0,0,0,0,0,0,0};
    const f32x4 fz = {0.f,0.f,0.f,0.f};
    f32x4 pv[2][4];
#pragma unroll
    for (int mt = 0; mt < 2; ++mt)
#pragma unroll
        for (int nf = 0; nf < 4; ++nf) pv[mt][nf] = fz;
    float den0 = 0.f, den1 = 0.f;

    for (int tile = 0; tile < 8; ++tile) {
        __syncthreads();     // stage(tile) complete
        // ---- logits: C[krow16][hq32] per wave (m-tile = w)
        const int arow = w * 16 + n;
        const char* ap = (const char*)ksm + arow * 512;
        const int asw = (arow & 7) << 4;
        f32x4 lac[2] = {fz, fz};
#pragma unroll
        for (int kk = 0; kk < 8; ++kk) {
            const bf16x8 a = *(const bf16x8*)(ap + ((kk * 64 + lg * 16) ^ asw));
            const int p = kk >> 2;
            const bool on = (((kk & 3) >> 1) == (n >> 3));
            const bf16x8 bq = on ? qf[p][kk & 1] : ZV;
            if (p == 0) lac[0] = __builtin_amdgcn_mfma_f32_16x16x32_bf16(a, bq, lac[0], 0, 0, 0);
            else        lac[1] = __builtin_amdgcn_mfma_f32_16x16x32_bf16(a, bq, lac[1], 0, 0, 0);
        }
        // ---- joint softmax over 32 (h,q) per k-row; rows live across 16 lanes
#pragma unroll
        for (int reg = 0; reg < 4; ++reg) {
            float m = fmaxf(lac[0][reg], lac[1][reg]);
#pragma unroll
            for (int off = 8; off; off >>= 1) m = fmaxf(m, __shfl_xor(m, off));
            const float e0 = __expf(lac[0][reg] - m);
            const float e1 = __expf(lac[1][reg] - m);
            float se = e0 + e1;
#pragma unroll
            for (int off = 8; off; off >>= 1) se += __shfl_xor(se, off);
            const float inv = 1.f / se;
            lac[0][reg] = e0 * inv; lac[1][reg] = e1 * inv;
            den0 += lac[0][reg];    den1 += lac[1][reg];
        }
        // ---- write P^T to LDS (bf16, swizzled); 4 consecutive k per store
        const int kb = w * 16 + lg * 4;
        {
            ushort4 p0, p1;
            p0.x = f2bf(lac[0][0]); p0.y = f2bf(lac[0][1]); p0.z = f2bf(lac[0][2]); p0.w = f2bf(lac[0][3]);
            p1.x = f2bf(lac[1][0]); p1.y = f2bf(lac[1][1]); p1.z = f2bf(lac[1][2]); p1.w = f2bf(lac[1][3]);
            *(ushort4*)((char*)psm + n * 128 + ((kb * 2) ^ ((n & 7) << 4))) = p0;
            *(ushort4*)((char*)psm + (16 + n) * 128 + ((kb * 2) ^ ((n & 7) << 4))) = p1;
        }
        if (write_p) {
            float* pp = pbuf + ((size_t)b * KK + k0g + tile * 64 + kb) * HQ;
#pragma unroll
            for (int reg = 0; reg < 4; ++reg) {
                pp[(size_t)reg * HQ + n] = lac[0][reg];
                pp[(size_t)reg * HQ + 16 + n] = lac[1][reg];
            }
        }
        __syncthreads();     // psm ready; ksm reads done
        if (tile < 7) stage_ks(tile + 1);
        // ---- PV: C[hq32][d64 per wave]
#pragma unroll
        for (int kk = 0; kk < 2; ++kk) {
            const int koff = kk * 64 + lg * 16;
            const bf16x8 a0 = *(const bf16x8*)((char*)psm + n * 128 + (koff ^ ((n & 7) << 4)));
            const bf16x8 a1 = *(const bf16x8*)((char*)psm + (16 + n) * 128 + (koff ^ ((n & 7) << 4)));
#pragma unroll
            for (int nf = 0; nf < 4; ++nf) {
                const int d = w * 64 + nf * 16 + n;
                const bf16x8 bv = *(const bf16x8*)((char*)vsm + d * 128 + (koff ^ ((d & 7) << 4)));
                pv[0][nf] = __builtin_amdgcn_mfma_f32_16x16x32_bf16(a0, bv, pv[0][nf], 0, 0, 0);
                pv[1][nf] = __builtin_amdgcn_mfma_f32_16x16x32_bf16(a1, bv, pv[1][nf], 0, 0, 0);
            }
        }
        __syncthreads();     // vsm/psm reads done
        if (tile < 7) stage_vs(tile + 1);
    }

    // ---- den reduce -> global partials
    den0 += __shfl_xor(den0, 16); den0 += __shfl_xor(den0, 32);
    den1 += __shfl_xor(den1, 16); den1 += __shfl_xor(den1, 32);
    if (l < 16) { dred[w][l] = den0; dred[w][16 + l] = den1; }
    __syncthreads();
    if (t < 32)
        denp[((size_t)b * NCH + chunk) * HQ + t] =
            dred[0][t] + dred[1][t] + dred[2][t] + dred[3][t];

    // ---- updates partials: wave w owns hq = w*8..w*8+7, d = w*64..w*64+63
    if ((lg >> 1) == (w & 1)) {
        const int mt = w >> 1;
#pragma unroll
        for (int nf = 0; nf < 4; ++nf) {
#pragma unroll
            for (int reg = 0; reg < 4; ++reg) {
                const int q = (lg & 1) * 4 + reg;
                updp[(((size_t)b * NCH + chunk) * Q + q) * D + w * 64 + nf * 16 + n] = pv[mt][nf][reg];
            }
        }
    }
}

// ---------------- reduce partials -> upd_bf (renormalized) ----------------
__global__ __launch_bounds__(256) void k_reduce(
    const float* __restrict__ updp, const float* __restrict__ denp,
    unsigned short* __restrict__ updbf)
{
    const int row = blockIdx.x, t = threadIdx.x;
    const int b = row >> 3, q = row & 7, h = t >> 6;
    float ds = 0.f, us = 0.f;
#pragma unroll
    for (int c = 0; c < NCH; ++c) {
        ds += denp[((size_t)b * NCH + c) * HQ + h * Q + q];
        us += updp[(((size_t)b * NCH + c) * Q + q) * D + t];
    }
    updbf[(size_t)row * D + t] = f2bf(us / (ds + (float)KK * EPS));
}

__global__ void k_den(const float* __restrict__ denp, float* __restrict__ invden)
{
    const int b = blockIdx.x, t = threadIdx.x;  // 32 threads
    float s = 0.f;
#pragma unroll
    for (int c = 0; c < NCH; ++c) s += denp[((size_t)b * NCH + c) * HQ + t];
    invden[b * HQ + t] = 1.f / (s + (float)KK * EPS);
}

// ---------------- GRU gemm: gg[512][1536] = [u|h] @ [Wih;Whh]^T ----------------
__global__ __launch_bounds__(256) void k_gru(
    const unsigned short* __restrict__ updbf, const unsigned short* __restrict__ slotsbf,
    const unsigned short* __restrict__ Wihbf, const unsigned short* __restrict__ Whhbf,
    float* __restrict__ gg)
{
    __shared__ unsigned short As[64 * 256];
    __shared__ unsigned short Bs[64 * 256];
    const int t = threadIdx.x, w = t >> 6, l = t & 63;
    const int rb = blockIdx.x / 24, nb = blockIdx.x % 24;
    const unsigned short* Asrc = (nb < 12) ? updbf : slotsbf;
    stage64x512B((const char*)Asrc, (size_t)rb * 64, 512, (char*)As, w, l);
    if (nb < 12) stage64x512B((const char*)Wihbf, (size_t)nb * 64, 512, (char*)Bs, w, l);
    else         stage64x512B((const char*)Whhbf, (size_t)(nb - 12) * 64, 512, (char*)Bs, w, l);
    __syncthreads();
    const int arow = w * 16 + (l & 15);
    const int asw = (l & 7) << 4;
    bf16x8 af[8];
#pragma unroll
    for (int kk = 0; kk < 8; ++kk)
        af[kk] = *(const bf16x8*)((char*)As + arow * 512 + ((kk * 64 + (l >> 4) * 16) ^ asw));
    const f32x4 fz = {0.f,0.f,0.f,0.f};
    f32x4 acc[4] = {fz, fz, fz, fz};
#pragma unroll
    for (int kk = 0; kk < 8; ++kk) {
        const int koff = kk * 64 + (l >> 4) * 16;
#pragma unroll
        for (int nf = 0; nf < 4; ++nf) {
            const int brow = nf * 16 + (l & 15);
            const bf16x8 bf_ = *(const bf16x8*)((char*)Bs + brow * 512 + (koff ^ ((brow & 7) << 4)));
            acc[nf] = __builtin_amdgcn_mfma_f32_16x16x32_bf16(af[kk], bf_, acc[nf], 0, 0, 0);
        }
    }
    const int colbase = (nb < 12) ? nb * 64 : 768 + (nb - 12) * 64;
#pragma unroll
    for (int nf = 0; nf < 4; ++nf) {
        const int col = colbase + nf * 16 + (l & 15);
#pragma unroll
        for (int reg = 0; reg < 4; ++reg) {
            const size_t row = (size_t)rb * 64 + w * 16 + (l >> 4) * 4 + reg;
            gg[row * 1536 + col] = acc[nf][reg];
        }
    }
}

// ---------------- gates + LN(mlp) ----------------
__global__ __launch_bounds__(256) void k_gates(
    const float* __restrict__ gg, const float* __restrict__ slots,
    const float* __restrict__ bih, const float* __restrict__ bhh,
    const float* __restrict__ lnw, const float* __restrict__ lnb,
    float* __restrict__ snew, unsigned short* __restrict__ mbf)
{
    const int row = blockIdx.x, t = threadIdx.x;
    __shared__ float red[8];
    const float* g = gg + (size_t)row * 1536;
    const float i_r = g[t]        + bih[t];
    const float i_z = g[256 + t]  + bih[256 + t];
    const float i_n = g[512 + t]  + bih[512 + t];
    const float h_r = g[768 + t]  + bhh[t];
    const float h_z = g[1024 + t] + bhh[256 + t];
    const float h_n = g[1280 + t] + bhh[512 + t];
    const float r = 1.f / (1.f + __expf(-(i_r + h_r)));
    const float z = 1.f / (1.f + __expf(-(i_z + h_z)));
    const float nn = tanhf(i_n + r * h_n);
    const float h0 = slots[(size_t)row * D + t];
    const float sn = (1.f - z) * nn + z * h0;
    snew[(size_t)row * D + t] = sn;
    float mu, rs;
    {
        float s = sn, ss = sn * sn;
#pragma unroll
        for (int off = 32; off; off >>= 1) { s += __shfl_xor(s, off); ss += __shfl_xor(ss, off); }
        if ((t & 63) == 0) { red[t >> 6] = s; red[4 + (t >> 6)] = ss; }
        __syncthreads();
        const float S  = red[0] + red[1] + red[2] + red[3];
        const float SS = red[4] + red[5] + red[6] + red[7];
        mu = S * (1.f / 256.f);
        rs = rsqrtf(SS * (1.f / 256.f) - mu * mu + LNE);
    }
    mbf[(size_t)row * D + t] = f2bf((sn - mu) * rs * lnw[t] + lnb[t]);
}

// ---------------- MLP gemm 1: hid = relu(m @ W1 + b1) ----------------
__global__ __launch_bounds__(256) void k_mlp1(
    const unsigned short* __restrict__ mbf, const unsigned short* __restrict__ W1T,
    const float* __restrict__ b1, unsigned short* __restrict__ hidbf)
{
    __shared__ unsigned short As[64 * 256];
    __shared__ unsigned short Bs[64 * 256];
    const int t = threadIdx.x, w = t >> 6, l = t & 63;
    const int rb = blockIdx.x >> 3, nb = blockIdx.x & 7;
    stage64x512B((const char*)mbf, (size_t)rb * 64, 512, (char*)As, w, l);
    stage64x512B((const char*)W1T, (size_t)nb * 64, 512, (char*)Bs, w, l);
    __syncthreads();
    const int arow = w * 16 + (l & 15);
    const int asw = (l & 7) << 4;
    bf16x8 af[8];
#pragma unroll
    for (int kk = 0; kk < 8; ++kk)
        af[kk] = *(const bf16x8*)((char*)As + arow * 512 + ((kk * 64 + (l >> 4) * 16) ^ asw));
    const f32x4 fz = {0.f,0.f,0.f,0.f};
    f32x4 acc[4] = {fz, fz, fz, fz};
#pragma unroll
    for (int kk = 0; kk < 8; ++kk) {
        const int koff = kk * 64 + (l >> 4) * 16;
#pragma unroll
        for (int nf = 0; nf < 4; ++nf) {
            const int brow = nf * 16 + (l & 15);
            const bf16x8 bf_ = *(const bf16x8*)((char*)Bs + brow * 512 + (koff ^ ((brow & 7) << 4)));
            acc[nf] = __builtin_amdgcn_mfma_f32_16x16x32_bf16(af[kk], bf_, acc[nf], 0, 0, 0);
        }
    }
#pragma unroll
    for (int nf = 0; nf < 4; ++nf) {
        const int col = nb * 64 + nf * 16 + (l & 15);
        const float bb = b1[col];
#pragma unroll
        for (int reg = 0; reg < 4; ++reg) {
            const size_t row = (size_t)rb * 64 + w * 16 + (l >> 4) * 4 + reg;
            hidbf[row * HM + col] = f2bf(fmaxf(acc[nf][reg] + bb, 0.f));
        }
    }
}

// ---------------- MLP gemm 2: slots = snew + hid @ W2 + b2 ----------------
__global__ __launch_bounds__(256) void k_mlp2(
    const unsigned short* __restrict__ hidbf, const unsigned short* __restrict__ W2T,
    const float* __restrict__ b2, const float* __restrict__ snew,
    float* __restrict__ slots, unsigned short* __restrict__ slotsbf)
{
    __shared__ unsigned short As[64 * 256];
    __shared__ unsigned short Bs[64 * 256];
    const int t = threadIdx.x, w = t >> 6, l = t & 63;
    const int rb = blockIdx.x >> 2, nb = blockIdx.x & 3;
    const f32x4 fz = {0.f,0.f,0.f,0.f};
    f32x4 acc[4] = {fz, fz, fz, fz};
    for (int c = 0; c < 2; ++c) {
        stage64x512B((const char*)hidbf + c * 512, (size_t)rb * 64, 1024, (char*)As, w, l);
        stage64x512B((const char*)W2T + c * 512, (size_t)nb * 64, 1024, (char*)Bs, w, l);
        __syncthreads();
        const int arow = w * 16 + (l & 15);
        const int asw = (l & 7) << 4;
        bf16x8 af[8];
#pragma unroll
        for (int kk = 0; kk < 8; ++kk)
            af[kk] = *(const bf16x8*)((char*)As + arow * 512 + ((kk * 64 + (l >> 4) * 16) ^ asw));
#pragma unroll
        for (int kk = 0; kk < 8; ++kk) {
            const int koff = kk * 64 + (l >> 4) * 16;
#pragma unroll
            for (int nf = 0; nf < 4; ++nf) {
                const int brow = nf * 16 + (l & 15);
                const bf16x8 bf_ = *(const bf16x8*)((char*)Bs + brow * 512 + (koff ^ ((brow & 7) << 4)));
                acc[nf] = __builtin_amdgcn_mfma_f32_16x16x32_bf16(af[kk], bf_, acc[nf], 0, 0, 0);
            }
        }
        __syncthreads();
    }
#pragma unroll
    for (int nf = 0; nf < 4; ++nf) {
        const int col = nb * 64 + nf * 16 + (l & 15);
        const float bb = b2[col];
#pragma unroll
        for (int reg = 0; reg < 4; ++reg) {
            const size_t row = (size_t)rb * 64 + w * 16 + (l >> 4) * 4 + reg;
            const float v = snew[row * D + col] + acc[nf][reg] + bb;
            slots[row * D + col] = v;
            slotsbf[row * D + col] = f2bf(v);
        }
    }
}

__global__ void k7_copy(const float* __restrict__ s, float* __restrict__ o)
{
    const int i = blockIdx.x * 256 + threadIdx.x;
    o[i] = s[i];
}

__global__ __launch_bounds__(256) void k7_attnout(
    const float* __restrict__ pbuf, const float* __restrict__ invden, float* __restrict__ out2)
{
    const int blk = blockIdx.x;
    const int b = blk >> 4;
    const int kk0 = (blk & 15) * 256;
    __shared__ float ps[256][33];
    __shared__ float inv[32];
    const int t = threadIdx.x;
    const float* pp = pbuf + ((size_t)b * KK + kk0) * HQ;
    for (int i = 0; i < 32; ++i) {
        const int idx = i * 256 + t;
        ps[idx >> 5][idx & 31] = pp[idx];
    }
    if (t < 32) inv[t] = invden[b * HQ + t];
    __syncthreads();
    float* o = out2 + (size_t)b * Q * KK + kk0 + t;
#pragma unroll
    for (int q = 0; q < 8; ++q) {
        float v = 0.f;
#pragma unroll
        for (int hh = 0; hh < 4; ++hh)
            v += (ps[t][hh * 8 + q] + EPS) * inv[hh * 8 + q];
        o[(size_t)q * KK] = v * 0.25f;
    }
}

extern "C" void kernel_launch(void* const* d_in, const int* in_sizes, int n_in,
                              void* d_out, int out_size, void* d_ws, size_t ws_size,
                              hipStream_t stream)
{
    const float* inputs  = (const float*)d_in[0];
    const float* slots0  = (const float*)d_in[1];
    const float* Wq      = (const float*)d_in[2];
    const float* Wk      = (const float*)d_in[3];
    const float* Wv      = (const float*)d_in[4];
    const float* ln_in_w = (const float*)d_in[5];
    const float* ln_in_b = (const float*)d_in[6];
    const float* ln_s_w  = (const float*)d_in[7];
    const float* ln_s_b  = (const float*)d_in[8];
    const float* ln_m_w  = (const float*)d_in[9];
    const float* ln_m_b  = (const float*)d_in[10];
    const float* gWih    = (const float*)d_in[11];
    const float* gWhh    = (const float*)d_in[12];
    const float* gbih    = (const float*)d_in[13];
    const float* gbhh    = (const float*)d_in[14];
    const float* W1      = (const float*)d_in[15];
    const float* b1      = (const float*)d_in[16];
    const float* W2      = (const float*)d_in[17];
    const float* b2      = (const float*)d_in[18];

    char* p = (char*)d_ws;
    unsigned short* kbuf  = (unsigned short*)p; p += (size_t)B * KK * D * 2;
    unsigned short* vbufT = (unsigned short*)p; p += (size_t)B * KK * D * 2;
    float* pbuf   = (float*)p; p += (size_t)B * KK * HQ * 4;
    float* updp   = (float*)p; p += (size_t)B * NCH * Q * D * 4;   // also aliased by gg
    float* denp   = (float*)p; p += (size_t)B * NCH * HQ * 4;
    float* invden = (float*)p; p += (size_t)B * HQ * 4;
    float* qbuf   = (float*)p; p += (size_t)B * Q * D * 4;
    float* slots  = (float*)p; p += (size_t)B * Q * D * 4;
    float* snew   = (float*)p; p += (size_t)B * Q * D * 4;
    unsigned short* slots_bf = (unsigned short*)p; p += (size_t)B * Q * D * 2;
    unsigned short* upd_bf   = (unsigned short*)p; p += (size_t)B * Q * D * 2;
    unsigned short* mbf      = (unsigned short*)p; p += (size_t)B * Q * D * 2;
    unsigned short* hidbf    = (unsigned short*)p; p += (size_t)B * Q * HM * 2;
    unsigned short* WkvT     = (unsigned short*)p; p += (size_t)512 * 256 * 2;
    unsigned short* Wihbf    = (unsigned short*)p; p += (size_t)768 * 256 * 2;
    unsigned short* Whhbf    = (unsigned short*)p; p += (size_t)768 * 256 * 2;
    unsigned short* W1T      = (unsigned short*)p; p += (size_t)HM * 256 * 2;
    unsigned short* W2T      = (unsigned short*)p; p += (size_t)256 * HM * 2;
    float* gg = updp;   // alias: gg[512][1536] (3.15MB) fits in updp (4.19MB); lifetimes disjoint

    k_init<<<(B * Q * D) / 256, 256, 0, stream>>>(slots0, slots, slots_bf);
    k0_wkv<<<512, 256, 0, stream>>>(Wk, Wv, WkvT);
    k0_cvt<<<768, 256, 0, stream>>>(gWih, Wihbf);
    k0_cvt<<<768, 256, 0, stream>>>(gWhh, Whhbf);
    k0_t1<<<512, 256, 0, stream>>>(W1, W1T);
    k0_t2<<<256, 256, 0, stream>>>(W2, W2T);
    k1_mfma<<<(B * KK) / 64, 256, 0, stream>>>(inputs, WkvT, ln_in_w, ln_in_b, kbuf, vbufT);
    for (int it = 0; it < 3; ++it) {
        k2_qproj<<<B * Q, 256, 0, stream>>>(slots, Wq, ln_s_w, ln_s_b, qbuf);
        k_attn<<<B * NCH, 256, 0, stream>>>(kbuf, vbufT, qbuf, updp, denp, pbuf, (it == 2) ? 1 : 0);
        k_reduce<<<B * Q, 256, 0, stream>>>(updp, denp, upd_bf);
        k_gru<<<8 * 24, 256, 0, stream>>>(upd_bf, slots_bf, Wihbf, Whhbf, gg);
        k_gates<<<B * Q, 256, 0, stream>>>(gg, slots, gbih, gbhh, ln_m_w, ln_m_b, snew, mbf);
        k_mlp1<<<8 * 8, 256, 0, stream>>>(mbf, W1T, b1, hidbf);
        k_mlp2<<<8 * 4, 256, 0, stream>>>(hidbf, W2T, b2, snew, slots, slots_bf);
    }
    k_den<<<B, 32, 0, stream>>>(denp, invden);
    k7_copy<<<(B * Q * D) / 256, 256, 0, stream>>>(slots, (float*)d_out);
    k7_attnout<<<B * (KK / 256), 256, 0, stream>>>(pbuf, invden, (float*)d_out + (size_t)B * Q * D);
}